// Round 16
// baseline (473.136 us; speedup 1.0000x reference)
//
#include <hip/hip_runtime.h>
#include <hip/hip_bf16.h>
#include <hip/hip_fp16.h>

// Problem constants (fixed by the reference setup)
#define NN   50000
#define EE   800000
#define FIN  128
#define CC   64
#define HH   4
#define GG   512
#define CAP  64          // per-node CSR capacity (Poisson(16) in-degree; P(>64) ~ 2e-18)
#define EBLK 1563        // ceil(EE / (256*2))

typedef _Float16 f16x8 __attribute__((ext_vector_type(8)));
typedef float    f32x4 __attribute__((ext_vector_type(4)));

__device__ __forceinline__ float leaky02(float x) { return x >= 0.f ? x : 0.2f * x; }
__device__ __forceinline__ float leaky01(float x) { return x >= 0.f ? x : 0.01f * x; }

// ---------------------------------------------------------------------------
// Fused: CSR build (uint16 entries, 2 edges/thread) + W fragment packing.
// Blocks [0,EBLK): edges. Blocks [EBLK, EBLK+32): pack W0/W1/W2 hi/lo.
// ---------------------------------------------------------------------------
__global__ __launch_bounds__(256) void build_csr_w(const int* __restrict__ ei,
                                                   int* __restrict__ deg,
                                                   unsigned short* __restrict__ csr,
                                                   const float* __restrict__ W0,
                                                   const float* __restrict__ W1,
                                                   const float* __restrict__ W2,
                                                   __half* __restrict__ w0ph, __half* __restrict__ w0pl,
                                                   __half* __restrict__ w1ph, __half* __restrict__ w1pl,
                                                   __half* __restrict__ w2ph, __half* __restrict__ w2pl) {
    const int b = blockIdx.x;
    if (b < EBLK) {
        int e = (b * 256 + threadIdx.x) * 2;
        if (e >= EE) return;
        int2 ss = *(const int2*)(ei + e);        // sources e, e+1
        int2 dd = *(const int2*)(ei + EE + e);   // dsts    e, e+1
        if ((unsigned)dd.x < NN && (unsigned)ss.x < NN) {
            int pos = atomicAdd(&deg[dd.x], 1);
            if (pos < CAP) csr[dd.x * CAP + pos] = (unsigned short)ss.x;
        }
        if ((unsigned)dd.y < NN && (unsigned)ss.y < NN) {
            int pos = atomicAdd(&deg[dd.y], 1);
            if (pos < CAP) csr[dd.y * CAP + pos] = (unsigned short)ss.y;
        }
        return;
    }
    // ---- W packing ----
    const int wb = b - EBLK;
    const float* W;
    __half *wph, *wpl;
    int id;
    if (wb < 16)      { W = W0; wph = w0ph; wpl = w0pl; id = wb * 256 + threadIdx.x; }
    else if (wb < 24) { W = W1; wph = w1ph; wpl = w1pl; id = (wb - 16) * 256 + threadIdx.x; }
    else              { W = W2; wph = w2ph; wpl = w2pl; id = (wb - 24) * 256 + threadIdx.x; }
    int lane = id & 63;
    int c    = (id >> 6) & 15;
    int kc   = id >> 10;
    int kbase = kc * 32 + (lane >> 4) * 8;
    int col   = c * 16 + (lane & 15);
    __half hi[8], lo[8];
#pragma unroll
    for (int j = 0; j < 8; ++j) {
        float v = W[(size_t)(kbase + j) * 256 + col];
        hi[j] = __float2half_rn(v);
        lo[j] = __float2half_rn(v - __half2float(hi[j]));
    }
    *(uint4*)(wph + (size_t)id * 8) = *(uint4*)hi;
    *(uint4*)(wpl + (size_t)id * 8) = *(uint4*)lo;
}

// ---------------------------------------------------------------------------
// MFMA GEMM: h = X @ W. Block 256 = 4 waves; wave owns 32 rows (two 16-row
// tiles) x 256 cols: each B fragment load feeds BOTH tiles (halves B-latency
// per row vs 16-row version). XF32: in-reg Markidis split, 3 MFMAs/tile-c.
// A frag: row=lane&15, k=(lane>>4)*8+j. C frag: col=lane&15, row=(lane>>4)*4+r.
// Epilogue per tile: fused al_s/al_d + LDS-staged coalesced fp16 h store.
// ---------------------------------------------------------------------------
template <int K, bool XF32>
__global__ __launch_bounds__(256, 2) void gemm_mfma(const void* __restrict__ xin,
                                                    const __half* __restrict__ wph,
                                                    const __half* __restrict__ wpl,
                                                    const float* __restrict__ a_src,
                                                    const float* __restrict__ a_dst,
                                                    __half* __restrict__ h_out,
                                                    float* __restrict__ al_s,
                                                    float* __restrict__ al_d) {
    __shared__ __half hst[4][16 * 256];            // 8KB per wave (reused per tile)
    const int t    = threadIdx.x;
    const int w    = t >> 6;
    const int lane = t & 63;
    const int r0   = blockIdx.x * 128 + w * 32;    // wave row base (32 rows)
    const int colL = lane & 15;
    const int rowg = lane >> 4;
    const int koff = rowg * 8;
    int ar0 = r0 + colL;       ar0 = ar0 < NN ? ar0 : NN - 1;
    int ar1 = r0 + 16 + colL;  ar1 = ar1 < NN ? ar1 : NN - 1;

    f32x4 acc[2][16];
#pragma unroll
    for (int m = 0; m < 2; ++m)
#pragma unroll
        for (int c = 0; c < 16; ++c) acc[m][c] = (f32x4){0.f, 0.f, 0.f, 0.f};

    for (int kc = 0; kc < K / 32; ++kc) {
        f16x8 ah0, al0, ah1, al1;
        if (XF32) {
            const float* xf = (const float*)xin;
            float v[8];
            *(float4*)&v[0] = *(const float4*)(xf + (size_t)ar0 * K + kc * 32 + koff);
            *(float4*)&v[4] = *(const float4*)(xf + (size_t)ar0 * K + kc * 32 + koff + 4);
#pragma unroll
            for (int j = 0; j < 8; ++j) {
                ah0[j] = (_Float16)v[j];
                al0[j] = (_Float16)(v[j] - (float)ah0[j]);
            }
            *(float4*)&v[0] = *(const float4*)(xf + (size_t)ar1 * K + kc * 32 + koff);
            *(float4*)&v[4] = *(const float4*)(xf + (size_t)ar1 * K + kc * 32 + koff + 4);
#pragma unroll
            for (int j = 0; j < 8; ++j) {
                ah1[j] = (_Float16)v[j];
                al1[j] = (_Float16)(v[j] - (float)ah1[j]);
            }
        } else {
            const __half* xh = (const __half*)xin;
            ah0 = *(const f16x8*)(xh + (size_t)ar0 * K + kc * 32 + koff);
            ah1 = *(const f16x8*)(xh + (size_t)ar1 * K + kc * 32 + koff);
        }
        const __half* bbase_h = wph + ((size_t)(kc * 16) * 64 + lane) * 8;
        const __half* bbase_l = wpl + ((size_t)(kc * 16) * 64 + lane) * 8;
#pragma unroll
        for (int c = 0; c < 16; ++c) {
            f16x8 bh = *(const f16x8*)(bbase_h + c * 512);
            f16x8 bl = *(const f16x8*)(bbase_l + c * 512);
            acc[0][c] = __builtin_amdgcn_mfma_f32_16x16x32_f16(ah0, bh, acc[0][c], 0, 0, 0);
            acc[0][c] = __builtin_amdgcn_mfma_f32_16x16x32_f16(ah0, bl, acc[0][c], 0, 0, 0);
            acc[1][c] = __builtin_amdgcn_mfma_f32_16x16x32_f16(ah1, bh, acc[1][c], 0, 0, 0);
            acc[1][c] = __builtin_amdgcn_mfma_f32_16x16x32_f16(ah1, bl, acc[1][c], 0, 0, 0);
            if (XF32) {
                acc[0][c] = __builtin_amdgcn_mfma_f32_16x16x32_f16(al0, bh, acc[0][c], 0, 0, 0);
                acc[1][c] = __builtin_amdgcn_mfma_f32_16x16x32_f16(al1, bh, acc[1][c], 0, 0, 0);
            }
        }
    }

    // ---- epilogue per 16-row tile: logits + LDS-staged coalesced store ----
    __half* my = hst[w];
#pragma unroll
    for (int m = 0; m < 2; ++m) {
        const int rowbase = r0 + m * 16;
        float aps[4][4], apd[4][4];
#pragma unroll
        for (int r = 0; r < 4; ++r)
#pragma unroll
            for (int h = 0; h < 4; ++h) { aps[r][h] = 0.f; apd[r][h] = 0.f; }
#pragma unroll
        for (int c = 0; c < 16; ++c) {
            const int col = c * 16 + colL;
            const float as = a_src[col];
            const float ad = a_dst[col];
            const int hh = c >> 2;
#pragma unroll
            for (int r = 0; r < 4; ++r) {
                aps[r][hh] = fmaf(acc[m][c][r], as, aps[r][hh]);
                apd[r][hh] = fmaf(acc[m][c][r], ad, apd[r][hh]);
            }
        }
#pragma unroll
        for (int r = 0; r < 4; ++r)
#pragma unroll
            for (int h = 0; h < 4; ++h) {
                float s = aps[r][h], d = apd[r][h];
#pragma unroll
                for (int off = 1; off <= 8; off <<= 1) {
                    s += __shfl_xor(s, off, 64);
                    d += __shfl_xor(d, off, 64);
                }
                aps[r][h] = s; apd[r][h] = d;
            }
        if (colL == 0) {
#pragma unroll
            for (int r = 0; r < 4; ++r) {
                const int row = rowbase + rowg * 4 + r;
                if (row < NN) {
#pragma unroll
                    for (int h = 0; h < 4; ++h) {
                        al_s[(size_t)row * 4 + h] = aps[r][h];
                        al_d[(size_t)row * 4 + h] = apd[r][h];
                    }
                }
            }
        }
        // LDS stage (XOR-swizzled 16B chunks) -> coalesced 16B global stores
#pragma unroll
        for (int c = 0; c < 16; ++c) {
            const int c16 = c * 2 + (colL >> 3);
#pragma unroll
            for (int r = 0; r < 4; ++r) {
                const int rl = rowg * 4 + r;
                my[rl * 256 + ((c16 ^ rl) * 8) + (colL & 7)] = __float2half_rn(acc[m][c][r]);
            }
        }
        {
            const int rl = lane >> 2;
            const int row = rowbase + rl;
            if (row < NN) {
#pragma unroll
                for (int j = 0; j < 8; ++j) {
                    const int chunk = (lane & 3) * 8 + j;
                    uint4 v = *(const uint4*)&my[rl * 256 + ((chunk ^ rl) * 8)];
                    *(uint4*)(h_out + (size_t)row * 256 + chunk * 8) = v;
                }
            }
        }
    }
}

// ---------------------------------------------------------------------------
// Per-dst segment softmax + aggregation. One wave per dst node. Softmax fp32;
// coef in LDS as dup'd half2; two virtual rows per iter (wave halves); fp16
// pk-fma accumulate; 32-bit byte offsets for the gather. Output fp16.
// ---------------------------------------------------------------------------
struct Half8 { __half2 h[4]; };

__global__ __launch_bounds__(256) void gat_aggregate(const __half* __restrict__ h_buf,
                                                     const float* __restrict__ al_s,
                                                     const float* __restrict__ al_d,
                                                     const int* __restrict__ deg,
                                                     const unsigned short* __restrict__ csr,
                                                     const float* __restrict__ bias,
                                                     __half* __restrict__ xb) {
    __shared__ __align__(16) __half2 els[4][66][4];
    const int w    = threadIdx.x >> 6;
    const int lane = threadIdx.x & 63;
    const int n    = blockIdx.x * 4 + w;
    const int d = min(deg[n], CAP);

    float4 ad4 = *(const float4*)(al_d + (size_t)n * 4);
    float4 as4 = *(const float4*)(al_s + (size_t)n * 4);
    const float* adp = (const float*)&ad4;
    const float* asp = (const float*)&as4;

    float aself[4];
#pragma unroll
    for (int h = 0; h < 4; ++h) aself[h] = leaky02(asp[h] + adp[h]);

    int s_lane = 0;
    float a_lane[4];
    if (lane < d) {
        s_lane = csr[n * CAP + lane];
        float4 s4 = *(const float4*)(al_s + (size_t)s_lane * 4);
        const float* sp = (const float*)&s4;
#pragma unroll
        for (int h = 0; h < 4; ++h) a_lane[h] = leaky02(sp[h] + adp[h]);
    } else {
#pragma unroll
        for (int h = 0; h < 4; ++h) a_lane[h] = -INFINITY;
    }

    float mx[4];
#pragma unroll
    for (int h = 0; h < 4; ++h) {
        mx[h] = fmaxf(aself[h], a_lane[h]);
#pragma unroll
        for (int off = 32; off; off >>= 1) mx[h] = fmaxf(mx[h], __shfl_xor(mx[h], off, 64));
    }

    float e[4], sm[4];
#pragma unroll
    for (int h = 0; h < 4; ++h) {
        e[h] = (lane < d) ? expf(a_lane[h] - mx[h]) : 0.f;
        sm[h] = e[h];
#pragma unroll
        for (int off = 32; off; off >>= 1) sm[h] += __shfl_xor(sm[h], off, 64);
    }
    float eself[4], inv[4];
#pragma unroll
    for (int h = 0; h < 4; ++h) {
        eself[h] = expf(aself[h] - mx[h]);
        inv[h] = 1.f / (sm[h] + eself[h] + 1e-16f);
    }
    if (lane < d) {
#pragma unroll
        for (int h = 0; h < 4; ++h) {
            float c = e[h] * inv[h];
            els[w][lane + 1][h] = __floats2half2_rn(c, c);
        }
    }
    if (lane == 0) {
#pragma unroll
        for (int h = 0; h < 4; ++h) {
            float c = eself[h] * inv[h];
            els[w][0][h] = __floats2half2_rn(c, c);
        }
    }

    const int q    = lane >> 5;
    const int m    = lane & 31;
    const int head = m >> 3;
    const char* __restrict__ hb = (const char*)h_buf + m * 16;   // 8 halves = 16B

    __half2 z = __floats2half2_rn(0.f, 0.f);
    __half2 acc0 = z, acc1 = z, acc2 = z, acc3 = z;
    const int count = d + 1;
    for (int t2 = 0; 2 * t2 < count; ++t2) {
        int v = 2 * t2 + q;
        int vi = v > 0 ? v - 1 : 0;
        int s = __shfl(s_lane, vi, 64);
        s = v == 0 ? n : s;
        if (v < count) {
            __half2 c2 = els[w][v][head];
            Half8 r = *(const Half8*)(hb + (size_t)((unsigned)s << 9));
            acc0 = __hfma2(r.h[0], c2, acc0);
            acc1 = __hfma2(r.h[1], c2, acc1);
            acc2 = __hfma2(r.h[2], c2, acc2);
            acc3 = __hfma2(r.h[3], c2, acc3);
        }
    }

    int i0 = __shfl_xor(*(int*)&acc0, 32, 64);
    int i1 = __shfl_xor(*(int*)&acc1, 32, 64);
    int i2 = __shfl_xor(*(int*)&acc2, 32, 64);
    int i3 = __shfl_xor(*(int*)&acc3, 32, 64);
    acc0 = __hadd2(acc0, *(__half2*)&i0);
    acc1 = __hadd2(acc1, *(__half2*)&i1);
    acc2 = __hadd2(acc2, *(__half2*)&i2);
    acc3 = __hadd2(acc3, *(__half2*)&i3);

    float ch[8];
    float2 f;
    f = __half22float2(acc0); ch[0] = f.x; ch[1] = f.y;
    f = __half22float2(acc1); ch[2] = f.x; ch[3] = f.y;
    f = __half22float2(acc2); ch[4] = f.x; ch[5] = f.y;
    f = __half22float2(acc3); ch[6] = f.x; ch[7] = f.y;
#pragma unroll
    for (int k = 0; k < 8; ++k) {
        ch[k] += __shfl_xor(ch[k], 8, 64);
        ch[k] += __shfl_xor(ch[k], 16, 64);
    }
    if (lane < 8) {
        __align__(16) __half h8[8];
#pragma unroll
        for (int k = 0; k < 8; ++k)
            h8[k] = __float2half_rn(leaky01(ch[k] * 0.25f + bias[lane * 8 + k]));
        *(uint4*)(xb + (size_t)n * 64 + lane * 8) = *(uint4*)h8;
    }
}

// ---------------------------------------------------------------------------
// Fused readout + MLP: one block per graph. Per-channel max/mean -> smem
// hid[128] -> leaky(hid@Wr1+br1) -> @Wr2+br2 -> out[g].
// ---------------------------------------------------------------------------
__global__ __launch_bounds__(256) void readout_mlp(const __half* __restrict__ x,
                                                   const int* __restrict__ batch,
                                                   const float* __restrict__ Wr1,
                                                   const float* __restrict__ br1,
                                                   const float* __restrict__ Wr2,
                                                   const float* __restrict__ br2,
                                                   float* __restrict__ out) {
    int g = blockIdx.x;
    int a = 0, b = NN;
    while (a < b) { int m = (a + b) >> 1; if (batch[m] < g) a = m + 1; else b = m; }
    int lo = a;
    a = lo; b = NN;
    while (a < b) { int m = (a + b) >> 1; if (batch[m] < g + 1) a = m + 1; else b = m; }
    int hi = a;

    int t = threadIdx.x, c = t & 63, s = t >> 6;
    float mx = -INFINITY, sm = 0.f;
    for (int n = lo + s; n < hi; n += 4) {
        float v = __half2float(x[(size_t)n * 64 + c]);
        mx = fmaxf(mx, v);
        sm += v;
    }
    __shared__ float smx[256], ssm[256];
    __shared__ float hid[128];
    __shared__ float part[4][64];
    smx[t] = mx; ssm[t] = sm;
    __syncthreads();
    if (t < 64) {
        mx = fmaxf(fmaxf(smx[t], smx[t + 64]), fmaxf(smx[t + 128], smx[t + 192]));
        sm = ssm[t] + ssm[t + 64] + ssm[t + 128] + ssm[t + 192];
        int cnt = hi - lo;
        hid[t] = mx;
        hid[64 + t] = sm / fmaxf((float)cnt, 1.0f);
    }
    __syncthreads();
    {
        int j = t & 63, q = t >> 6;
        float p = 0.f;
#pragma unroll
        for (int i = 0; i < 32; ++i)
            p = fmaf(hid[q * 32 + i], Wr1[(q * 32 + i) * 64 + j], p);
        part[q][j] = p;
    }
    __syncthreads();
    if (t < 64) {
        float v = br1[t] + ((part[0][t] + part[1][t]) + (part[2][t] + part[3][t]));
        v = leaky01(v);
        float tv = v * Wr2[t];
#pragma unroll
        for (int off = 32; off; off >>= 1) tv += __shfl_xor(tv, off, 64);
        if (t == 0) out[g] = tv + br2[0];
    }
}

// ---------------------------------------------------------------------------
extern "C" void kernel_launch(void* const* d_in, const int* in_sizes, int n_in,
                              void* d_out, int out_size, void* d_ws, size_t ws_size,
                              hipStream_t stream) {
    const float* x   = (const float*)d_in[0];
    const int* ei    = (const int*)d_in[1];
    const int* batch = (const int*)d_in[3];
    const float* W0  = (const float*)d_in[4];
    const float* as0 = (const float*)d_in[5];
    const float* ad0 = (const float*)d_in[6];
    const float* b0  = (const float*)d_in[7];
    const float* W1  = (const float*)d_in[8];
    const float* as1 = (const float*)d_in[9];
    const float* ad1 = (const float*)d_in[10];
    const float* b1  = (const float*)d_in[11];
    const float* W2  = (const float*)d_in[12];
    const float* as2 = (const float*)d_in[13];
    const float* ad2 = (const float*)d_in[14];
    const float* b2  = (const float*)d_in[15];
    const float* Wr1 = (const float*)d_in[16];
    const float* br1 = (const float*)d_in[17];
    const float* Wr2 = (const float*)d_in[18];
    const float* br2 = (const float*)d_in[19];
    float* out = (float*)d_out;

    // workspace layout (halves unless noted)
    __half* h_buf = (__half*)d_ws;                          // NN*256 (25.6MB)
    __half* xb    = h_buf + (size_t)NN * 256;               // NN*64  (6.4MB)
    __half* w0ph  = xb + (size_t)NN * 64;                   // 32768
    __half* w0pl  = w0ph + 32768;
    __half* w1ph  = w0pl + 32768;                           // 16384
    __half* w1pl  = w1ph + 16384;
    __half* w2ph  = w1pl + 16384;
    __half* w2pl  = w2ph + 16384;
    float*  al_s  = (float*)(w2pl + 16384);                 // NN*4
    float*  al_d  = al_s + (size_t)NN * 4;                  // NN*4
    int*    deg   = (int*)(al_d + (size_t)NN * 4);          // NN
    unsigned short* csr = (unsigned short*)(deg + NN);      // NN*CAP (6.4MB)

    hipMemsetAsync(deg, 0, NN * sizeof(int), stream);
    build_csr_w<<<EBLK + 32, 256, 0, stream>>>(ei, deg, csr, W0, W1, W2,
                                               w0ph, w0pl, w1ph, w1pl, w2ph, w2pl);

    const int gemm_grid = (NN + 127) / 128;
    const int agg_grid  = (NN + 3) / 4;

    // layer 0 (fp32 x, Markidis 3-mul)
    gemm_mfma<FIN, true><<<gemm_grid, 256, 0, stream>>>(x, w0ph, w0pl, as0, ad0, h_buf, al_s, al_d);
    gat_aggregate<<<agg_grid, 256, 0, stream>>>(h_buf, al_s, al_d, deg, csr, b0, xb);
    // layer 1 (fp16 x, 2-mul)
    gemm_mfma<CC, false><<<gemm_grid, 256, 0, stream>>>(xb, w1ph, w1pl, as1, ad1, h_buf, al_s, al_d);
    gat_aggregate<<<agg_grid, 256, 0, stream>>>(h_buf, al_s, al_d, deg, csr, b1, xb);
    // layer 2
    gemm_mfma<CC, false><<<gemm_grid, 256, 0, stream>>>(xb, w2ph, w2pl, as2, ad2, h_buf, al_s, al_d);
    gat_aggregate<<<agg_grid, 256, 0, stream>>>(h_buf, al_s, al_d, deg, csr, b2, xb);

    // fused readout + MLP
    readout_mlp<<<GG, 256, 0, stream>>>(xb, batch, Wr1, br1, Wr2, br2, out);
}